// Round 12
// baseline (123.389 us; speedup 1.0000x reference)
//
#include <hip/hip_runtime.h>
#include <hip/hip_fp16.h>

// Problem constants
#define BATCH   4
#define SEQ     4096
#define DMODEL  1024
#define HDIM    120
#define ROWS_TOTAL (BATCH * SEQ)       // 16384
#define TPB     256                    // 16-row tiles per batch (SEQ/16)

typedef float f32x4 __attribute__((ext_vector_type(4)));
typedef short s16x8 __attribute__((ext_vector_type(8)));

// F layout (fragment-ordered ctx): s16x8 F[global_tile][ks][lane]
//   = ctx_n[tile*16 + (lane&15)][ks*32 + (lane>>4)*8 .. +8]  (bf16)
#define FRAG_PER_B ((size_t)TPB * 4 * 64)
// WF layout (fragment-ordered Wq*wt, bf16): s16x8 WF[(ct*32+ks)*64 + lane]

static __device__ __forceinline__ unsigned short f2bf(float f) {
    unsigned u = __float_as_uint(f);
    u += 0x7FFFu + ((u >> 16) & 1u);   // RNE
    return (unsigned short)(u >> 16);
}
static __device__ __forceinline__ s16x8 pack2x4(f32x4 lo, f32x4 hi) {
    s16x8 r;
#pragma unroll
    for (int i = 0; i < 4; ++i) r[i] = (short)f2bf(lo[i]);
#pragma unroll
    for (int i = 0; i < 4; ++i) r[4 + i] = (short)f2bf(hi[i]);
    return r;
}

// ---------------------------------------------------------------------------
// Kernel W: Wq [120][1024] f32 -> WF fragment-ordered bf16, wt folded in.
// ---------------------------------------------------------------------------
__global__ __launch_bounds__(64)
void wq_frag_kernel(const float* __restrict__ Wq, const float* __restrict__ wt,
                    s16x8* __restrict__ WF)
{
    const int lane = threadIdx.x;
    const int l15  = lane & 15;
    const int l4   = lane >> 4;
    const int ct   = blockIdx.x >> 5;
    const int ks   = blockIdx.x & 31;
    const int col  = ct * 16 + l15;

    f32x4 lo = (f32x4){0.f,0.f,0.f,0.f}, hi = lo;
    if (col < HDIM) {
        const float w = wt[col];
        const float* src = Wq + (size_t)col * DMODEL + ks * 32 + l4 * 8;
        lo = *(const f32x4*)(src);
        hi = *(const f32x4*)(src + 4);
#pragma unroll
        for (int i = 0; i < 4; ++i) { lo[i] *= w; hi[i] *= w; }
    }
    WF[((size_t)(ct * 32 + ks)) * 64 + lane] = pack2x4(lo, hi);
}

// ---------------------------------------------------------------------------
// Kernel A (unchanged from R11): context = query @ (Wq*wt)^T + bq*wt,
// row-L2-normalized -> F. Full-line query staging, contiguous WF loads.
// ---------------------------------------------------------------------------
__global__ __launch_bounds__(512)
void ctx_norm_kernel(const float* __restrict__ query,
                     const s16x8* __restrict__ WF,
                     const float* __restrict__ bq,
                     const float* __restrict__ wt,
                     s16x8* __restrict__ F)
{
    __shared__ unsigned short lA[2][64 * 40];
    __shared__ float lsq[64][2];
    __shared__ unsigned short lt[64][136];

    const int tid  = threadIdx.x;
    const int lane = tid & 63;
    const int wv   = tid >> 6;
    const int wr   = wv & 3;
    const int wc   = wv >> 2;
    const int l15  = lane & 15;
    const int l4   = lane >> 4;
    const int row0 = blockIdx.x * 64;

    const int arow = tid >> 3, achk = tid & 7;
    const float* aload = query + (size_t)(row0 + arow) * DMODEL + achk * 4;

    f32x4 acc[4];
#pragma unroll
    for (int n = 0; n < 4; ++n) acc[n] = (f32x4){0.f,0.f,0.f,0.f};

    f32x4 pr = *(const f32x4*)(aload);
    {
        const unsigned u0 = (unsigned)f2bf(pr[0]) | ((unsigned)f2bf(pr[1]) << 16);
        const unsigned u1 = (unsigned)f2bf(pr[2]) | ((unsigned)f2bf(pr[3]) << 16);
        *(uint2*)&lA[0][arow * 40 + achk * 4] = make_uint2(u0, u1);
    }

    for (int ks = 0; ks < 32; ++ks) {
        __syncthreads();
        if (ks + 1 < 32) pr = *(const f32x4*)(aload + (ks + 1) * 32);
        const int buf = ks & 1;
        const s16x8 a = *(const s16x8*)&lA[buf][(wr * 16 + l15) * 40 + l4 * 8];
#pragma unroll
        for (int n = 0; n < 4; ++n) {
            const s16x8 bfr = WF[((size_t)((wc * 4 + n) * 32 + ks)) * 64 + lane];
            acc[n] = __builtin_amdgcn_mfma_f32_16x16x32_bf16(a, bfr, acc[n], 0, 0, 0);
        }
        if (ks + 1 < 32) {
            const unsigned u0 = (unsigned)f2bf(pr[0]) | ((unsigned)f2bf(pr[1]) << 16);
            const unsigned u1 = (unsigned)f2bf(pr[2]) | ((unsigned)f2bf(pr[3]) << 16);
            *(uint2*)&lA[buf ^ 1][arow * 40 + achk * 4] = make_uint2(u0, u1);
        }
    }

    float sumsq[4] = {0.f,0.f,0.f,0.f};
#pragma unroll
    for (int n = 0; n < 4; ++n) {
        const int col = wc * 64 + n * 16 + l15;
        const float bqv = (col < HDIM) ? bq[col] * wt[col] : 0.f;
#pragma unroll
        for (int r = 0; r < 4; ++r) {
            const float v = acc[n][r] + bqv;
            acc[n][r] = v;
            sumsq[r] += v * v;
        }
    }
#pragma unroll
    for (int r = 0; r < 4; ++r) {
        float s = sumsq[r];
        s += __shfl_xor(s, 1);
        s += __shfl_xor(s, 2);
        s += __shfl_xor(s, 4);
        s += __shfl_xor(s, 8);
        sumsq[r] = s;
    }
    if (l15 == 0) {
#pragma unroll
        for (int r = 0; r < 4; ++r)
            lsq[wr * 16 + l4 * 4 + r][wc] = sumsq[r];
    }
    __syncthreads();
#pragma unroll
    for (int r = 0; r < 4; ++r) {
        const int lr = wr * 16 + l4 * 4 + r;
        const float s = lsq[lr][0] + lsq[lr][1];
        const float rinv = 1.f / fmaxf(sqrtf(s), 1e-12f);
#pragma unroll
        for (int n = 0; n < 4; ++n)
            lt[lr][wc * 64 + n * 16 + l15] = f2bf(acc[n][r] * rinv);
    }
    __syncthreads();
#pragma unroll
    for (int q = 0; q < 2; ++q) {
        const int idx = wv * 2 + q;
        const int tl  = idx >> 2;
        const int k4  = idx & 3;
        const s16x8 fr = *(const s16x8*)&lt[tl * 16 + l15][k4 * 32 + l4 * 8];
        F[((size_t)(blockIdx.x * 4 + tl) * 4 + k4) * 64 + lane] = fr;
    }
}

// ---------------------------------------------------------------------------
// Kernel B v5: 1024 blocks x 512 thr (8 waves), launch_bounds(512,4) ->
// 2 blocks/CU: compute of one block overlaps HBM writes of the other.
// Block = one 16-row tile x 4096 cols. Wave cg handles tiles tc = t*8+cg
// (t=0..31, interleaved so every 1024-col chunk has 8 tiles from each wave).
// exp stash in REGISTERS (packed f16 pairs, 64 VGPR). After rowsum: 4 chunks
// of {dump 8 tiles -> 32KB LDS (swizzled) -> barrier -> each wave writes 2
// full rows as contiguous 1KB NT stores -> barrier}.
// ---------------------------------------------------------------------------
#define LOADT5(dst, t) { const s16x8* _p = base + (size_t)(t) * 2048;          \
    dst[0] = _p[0]; dst[1] = _p[64]; dst[2] = _p[128]; dst[3] = _p[192]; }

#define COMPT5(src, t) { f32x4 _a = (f32x4){0.f, 0.f, 0.f, 0.f};               \
    _a = __builtin_amdgcn_mfma_f32_16x16x32_bf16(src[0], rfrag[0], _a, 0,0,0); \
    _a = __builtin_amdgcn_mfma_f32_16x16x32_bf16(src[1], rfrag[1], _a, 0,0,0); \
    _a = __builtin_amdgcn_mfma_f32_16x16x32_bf16(src[2], rfrag[2], _a, 0,0,0); \
    _a = __builtin_amdgcn_mfma_f32_16x16x32_bf16(src[3], rfrag[3], _a, 0,0,0); \
    const float _e0 = __expf(_a[0]), _e1 = __expf(_a[1]);                      \
    const float _e2 = __expf(_a[2]), _e3 = __expf(_a[3]);                      \
    rs += (_e0 + _e1) + (_e2 + _e3);                                           \
    const __half2 _h01 = __floats2half2_rn(_e0, _e1);                          \
    const __half2 _h23 = __floats2half2_rn(_e2, _e3);                          \
    ex0[t] = *(const unsigned*)&_h01;                                          \
    ex1[t] = *(const unsigned*)&_h23; }

__global__ __launch_bounds__(512, 4)
void gram_fused_kernel(const s16x8* __restrict__ F, float* __restrict__ out)
{
    __shared__ unsigned short lsB[16 * 1024];   // 32 KB bounce, swizzled
    __shared__ float lsum[16][8];

    const int tid  = threadIdx.x;
    const int lane = tid & 63;
    const int cg   = tid >> 6;          // wave 0..7
    const int l15  = lane & 15;
    const int l4   = lane >> 4;
    char* lsb = (char*)&lsB[0];

    // XCD swizzle (bijective on 1024): 128 contiguous row-tiles per XCD
    const int u    = ((blockIdx.x & 7) << 7) | (blockIdx.x >> 3);
    const int b    = u >> 8;
    const int tr   = u & 255;
    const s16x8* Fb = F + (size_t)b * FRAG_PER_B;

    s16x8 rfrag[4];
#pragma unroll
    for (int ks = 0; ks < 4; ++ks) rfrag[ks] = Fb[((size_t)tr * 4 + ks) * 64 + lane];

    // wave cg's tile sequence: tc = t*8 + cg -> offset tc*256 = t*2048 + cg*256
    const s16x8* base = Fb + (size_t)cg * 256 + lane;

    unsigned ex0[32], ex1[32];
    float rs = 0.f;
    s16x8 cf0[4], cf1[4];

    LOADT5(cf0, 0)
    LOADT5(cf1, 1)
#pragma unroll
    for (int i = 0; i < 16; ++i) {
        { COMPT5(cf0, 2 * i)     if (2 * i + 2 < 32) LOADT5(cf0, 2 * i + 2) }
        { COMPT5(cf1, 2 * i + 1) if (2 * i + 3 < 32) LOADT5(cf1, 2 * i + 3) }
    }

    // rowsum: lane's rs covers row l15 over wave cg's 512 cols
    rs += __shfl_xor(rs, 16);
    rs += __shfl_xor(rs, 32);
    if (lane < 16) lsum[lane][cg] = rs;
    __syncthreads();

    // each wave owns output rows {cg*2, cg*2+1}
    const int r0 = cg * 2, r1 = cg * 2 + 1;
    float s0 = 0.f, s1 = 0.f;
#pragma unroll
    for (int w = 0; w < 8; ++w) { s0 += lsum[r0][w]; s1 += lsum[r1][w]; }
    const float rv0 = 1.f / s0;
    const float rv1 = 1.f / s1;

    float* ob0 = out + ((size_t)b * SEQ + tr * 16 + r0) * SEQ;
    float* ob1 = out + ((size_t)b * SEQ + tr * 16 + r1) * SEQ;
    const unsigned wswz = (unsigned)((l15 & 7) << 4);
    const unsigned rswz0 = (unsigned)((r0 & 7) << 4);
    const unsigned rswz1 = (unsigned)((r1 & 7) << 4);

#pragma unroll
    for (int c = 0; c < 4; ++c) {
        if (c > 0) __syncthreads();     // prior chunk's reads done
        // dump 8 tiles (local tile idx = i*8+cg within the chunk)
#pragma unroll
        for (int i = 0; i < 8; ++i) {
            const int t = c * 8 + i;
            const unsigned byte = ((unsigned)(l15 * 2048 + (i * 8 + cg) * 32 + l4 * 8)) ^ wswz;
            *(uint2*)(lsb + byte) = make_uint2(ex0[t], ex1[t]);
        }
        __syncthreads();
        // write 2 full rows, 4x 1KB contiguous NT stores each
#pragma unroll
        for (int it = 0; it < 4; ++it) {
            const unsigned byA = ((unsigned)(r0 * 2048 + it * 512 + lane * 8)) ^ rswz0;
            const uint2 dA = *(const uint2*)(lsb + byA);
            const float2 a01 = __half22float2(*(const __half2*)&dA.x);
            const float2 a23 = __half22float2(*(const __half2*)&dA.y);
            f32x4 pA;
            pA[0] = a01.x * rv0; pA[1] = a01.y * rv0;
            pA[2] = a23.x * rv0; pA[3] = a23.y * rv0;
            __builtin_nontemporal_store(pA, (f32x4*)(ob0 + c * 1024 + it * 256 + lane * 4));

            const unsigned byB = ((unsigned)(r1 * 2048 + it * 512 + lane * 8)) ^ rswz1;
            const uint2 dB = *(const uint2*)(lsb + byB);
            const float2 b01 = __half22float2(*(const __half2*)&dB.x);
            const float2 b23 = __half22float2(*(const __half2*)&dB.y);
            f32x4 pB;
            pB[0] = b01.x * rv1; pB[1] = b01.y * rv1;
            pB[2] = b23.x * rv1; pB[3] = b23.y * rv1;
            __builtin_nontemporal_store(pB, (f32x4*)(ob1 + c * 1024 + it * 256 + lane * 4));
        }
    }
}

extern "C" void kernel_launch(void* const* d_in, const int* in_sizes, int n_in,
                              void* d_out, int out_size, void* d_ws, size_t ws_size,
                              hipStream_t stream)
{
    const float* query = (const float*)d_in[0];
    // d_in[1] = key (unused by the forward)
    const float* Wq    = (const float*)d_in[2];
    const float* bq    = (const float*)d_in[3];
    const float* wt    = (const float*)d_in[4];
    float* out = (float*)d_out;
    s16x8* F  = (s16x8*)d_ws;                               // 4 MiB
    s16x8* WF = (s16x8*)((char*)d_ws + (size_t)4 * 1024 * 1024);  // 256 KiB

    wq_frag_kernel<<<dim3(256), dim3(64), 0, stream>>>(Wq, wt, WF);
    ctx_norm_kernel<<<dim3(ROWS_TOTAL / 64), dim3(512), 0, stream>>>(query, WF, bq, wt, F);
    gram_fused_kernel<<<dim3(BATCH * TPB), dim3(512), 0, stream>>>(F, out);
}

// Round 13
// 120.082 us; speedup vs baseline: 1.0275x; 1.0275x over previous
//
#include <hip/hip_runtime.h>
#include <hip/hip_fp16.h>

// Problem constants
#define BATCH   4
#define SEQ     4096
#define DMODEL  1024
#define HDIM    120
#define ROWS_TOTAL (BATCH * SEQ)       // 16384
#define TPB     256                    // 16-row tiles per batch (SEQ/16)

typedef float f32x4 __attribute__((ext_vector_type(4)));
typedef short s16x8 __attribute__((ext_vector_type(8)));

// F layout (fragment-ordered ctx): s16x8 F[global_tile][ks][lane]
//   = ctx_n[tile*16 + (lane&15)][ks*32 + (lane>>4)*8 .. +8]  (bf16)
#define FRAG_PER_B ((size_t)TPB * 4 * 64)
// WF layout (fragment-ordered Wq*wt, bf16): s16x8 WF[(ct*32+ks)*64 + lane]

static __device__ __forceinline__ unsigned short f2bf(float f) {
    unsigned u = __float_as_uint(f);
    u += 0x7FFFu + ((u >> 16) & 1u);   // RNE
    return (unsigned short)(u >> 16);
}
static __device__ __forceinline__ s16x8 pack2x4(f32x4 lo, f32x4 hi) {
    s16x8 r;
#pragma unroll
    for (int i = 0; i < 4; ++i) r[i] = (short)f2bf(lo[i]);
#pragma unroll
    for (int i = 0; i < 4; ++i) r[4 + i] = (short)f2bf(hi[i]);
    return r;
}

// ---------------------------------------------------------------------------
// Kernel W: Wq [120][1024] f32 -> WF fragment-ordered bf16, wt folded in.
// ---------------------------------------------------------------------------
__global__ __launch_bounds__(64)
void wq_frag_kernel(const float* __restrict__ Wq, const float* __restrict__ wt,
                    s16x8* __restrict__ WF)
{
    const int lane = threadIdx.x;
    const int l15  = lane & 15;
    const int l4   = lane >> 4;
    const int ct   = blockIdx.x >> 5;
    const int ks   = blockIdx.x & 31;
    const int col  = ct * 16 + l15;

    f32x4 lo = (f32x4){0.f,0.f,0.f,0.f}, hi = lo;
    if (col < HDIM) {
        const float w = wt[col];
        const float* src = Wq + (size_t)col * DMODEL + ks * 32 + l4 * 8;
        lo = *(const f32x4*)(src);
        hi = *(const f32x4*)(src + 4);
#pragma unroll
        for (int i = 0; i < 4; ++i) { lo[i] *= w; hi[i] *= w; }
    }
    WF[((size_t)(ct * 32 + ks)) * 64 + lane] = pack2x4(lo, hi);
}

// ---------------------------------------------------------------------------
// Kernel A (unchanged from R11): context = query @ (Wq*wt)^T + bq*wt,
// row-L2-normalized -> F. Full-line query staging, contiguous WF loads.
// ---------------------------------------------------------------------------
__global__ __launch_bounds__(512)
void ctx_norm_kernel(const float* __restrict__ query,
                     const s16x8* __restrict__ WF,
                     const float* __restrict__ bq,
                     const float* __restrict__ wt,
                     s16x8* __restrict__ F)
{
    __shared__ unsigned short lA[2][64 * 40];
    __shared__ float lsq[64][2];
    __shared__ unsigned short lt[64][136];

    const int tid  = threadIdx.x;
    const int lane = tid & 63;
    const int wv   = tid >> 6;
    const int wr   = wv & 3;
    const int wc   = wv >> 2;
    const int l15  = lane & 15;
    const int l4   = lane >> 4;
    const int row0 = blockIdx.x * 64;

    const int arow = tid >> 3, achk = tid & 7;
    const float* aload = query + (size_t)(row0 + arow) * DMODEL + achk * 4;

    f32x4 acc[4];
#pragma unroll
    for (int n = 0; n < 4; ++n) acc[n] = (f32x4){0.f,0.f,0.f,0.f};

    f32x4 pr = *(const f32x4*)(aload);
    {
        const unsigned u0 = (unsigned)f2bf(pr[0]) | ((unsigned)f2bf(pr[1]) << 16);
        const unsigned u1 = (unsigned)f2bf(pr[2]) | ((unsigned)f2bf(pr[3]) << 16);
        *(uint2*)&lA[0][arow * 40 + achk * 4] = make_uint2(u0, u1);
    }

    for (int ks = 0; ks < 32; ++ks) {
        __syncthreads();
        if (ks + 1 < 32) pr = *(const f32x4*)(aload + (ks + 1) * 32);
        const int buf = ks & 1;
        const s16x8 a = *(const s16x8*)&lA[buf][(wr * 16 + l15) * 40 + l4 * 8];
#pragma unroll
        for (int n = 0; n < 4; ++n) {
            const s16x8 bfr = WF[((size_t)((wc * 4 + n) * 32 + ks)) * 64 + lane];
            acc[n] = __builtin_amdgcn_mfma_f32_16x16x32_bf16(a, bfr, acc[n], 0, 0, 0);
        }
        if (ks + 1 < 32) {
            const unsigned u0 = (unsigned)f2bf(pr[0]) | ((unsigned)f2bf(pr[1]) << 16);
            const unsigned u1 = (unsigned)f2bf(pr[2]) | ((unsigned)f2bf(pr[3]) << 16);
            *(uint2*)&lA[buf ^ 1][arow * 40 + achk * 4] = make_uint2(u0, u1);
        }
    }

    float sumsq[4] = {0.f,0.f,0.f,0.f};
#pragma unroll
    for (int n = 0; n < 4; ++n) {
        const int col = wc * 64 + n * 16 + l15;
        const float bqv = (col < HDIM) ? bq[col] * wt[col] : 0.f;
#pragma unroll
        for (int r = 0; r < 4; ++r) {
            const float v = acc[n][r] + bqv;
            acc[n][r] = v;
            sumsq[r] += v * v;
        }
    }
#pragma unroll
    for (int r = 0; r < 4; ++r) {
        float s = sumsq[r];
        s += __shfl_xor(s, 1);
        s += __shfl_xor(s, 2);
        s += __shfl_xor(s, 4);
        s += __shfl_xor(s, 8);
        sumsq[r] = s;
    }
    if (l15 == 0) {
#pragma unroll
        for (int r = 0; r < 4; ++r)
            lsq[wr * 16 + l4 * 4 + r][wc] = sumsq[r];
    }
    __syncthreads();
#pragma unroll
    for (int r = 0; r < 4; ++r) {
        const int lr = wr * 16 + l4 * 4 + r;
        const float s = lsq[lr][0] + lsq[lr][1];
        const float rinv = 1.f / fmaxf(sqrtf(s), 1e-12f);
#pragma unroll
        for (int n = 0; n < 4; ++n)
            lt[lr][wc * 64 + n * 16 + l15] = f2bf(acc[n][r] * rinv);
    }
    __syncthreads();
#pragma unroll
    for (int q = 0; q < 2; ++q) {
        const int idx = wv * 2 + q;
        const int tl  = idx >> 2;
        const int k4  = idx & 3;
        const s16x8 fr = *(const s16x8*)&lt[tl * 16 + l15][k4 * 32 + l4 * 8];
        F[((size_t)(blockIdx.x * 4 + tl) * 4 + k4) * 64 + lane] = fr;
    }
}

// ---------------------------------------------------------------------------
// Kernel B v6: v5 structure, SPILL-FREE. 1024 blocks x 512 thr, 2 blocks/CU
// (launch_bounds(512,4) -> VGPR cap 128; budget: ex 64 + cf 16 + rfrag 16 +
// temps ~20 = ~116). Single cf buffer — per-tile L2 latency covered by TLP
// (4 waves/SIMD) and by the co-resident block's write phase (the overlap this
// structure exists for). Chunked 32KB LDS bounce -> full-row 1KB NT stores.
// ---------------------------------------------------------------------------
#define LOADT5(dst, t) { const s16x8* _p = base + (size_t)(t) * 2048;          \
    dst[0] = _p[0]; dst[1] = _p[64]; dst[2] = _p[128]; dst[3] = _p[192]; }

#define COMPT5(src, t) { f32x4 _a = (f32x4){0.f, 0.f, 0.f, 0.f};               \
    _a = __builtin_amdgcn_mfma_f32_16x16x32_bf16(src[0], rfrag[0], _a, 0,0,0); \
    _a = __builtin_amdgcn_mfma_f32_16x16x32_bf16(src[1], rfrag[1], _a, 0,0,0); \
    _a = __builtin_amdgcn_mfma_f32_16x16x32_bf16(src[2], rfrag[2], _a, 0,0,0); \
    _a = __builtin_amdgcn_mfma_f32_16x16x32_bf16(src[3], rfrag[3], _a, 0,0,0); \
    const float _e0 = __expf(_a[0]), _e1 = __expf(_a[1]);                      \
    const float _e2 = __expf(_a[2]), _e3 = __expf(_a[3]);                      \
    rs += (_e0 + _e1) + (_e2 + _e3);                                           \
    const __half2 _h01 = __floats2half2_rn(_e0, _e1);                          \
    const __half2 _h23 = __floats2half2_rn(_e2, _e3);                          \
    ex0[t] = *(const unsigned*)&_h01;                                          \
    ex1[t] = *(const unsigned*)&_h23; }

__global__ __launch_bounds__(512, 4)
void gram_fused_kernel(const s16x8* __restrict__ F, float* __restrict__ out)
{
    __shared__ unsigned short lsB[16 * 1024];   // 32 KB bounce, swizzled
    __shared__ float lsum[16][8];

    const int tid  = threadIdx.x;
    const int lane = tid & 63;
    const int cg   = tid >> 6;          // wave 0..7
    const int l15  = lane & 15;
    const int l4   = lane >> 4;
    char* lsb = (char*)&lsB[0];

    // XCD swizzle (bijective on 1024): 128 contiguous row-tiles per XCD
    const int u    = ((blockIdx.x & 7) << 7) | (blockIdx.x >> 3);
    const int b    = u >> 8;
    const int tr   = u & 255;
    const s16x8* Fb = F + (size_t)b * FRAG_PER_B;

    s16x8 rfrag[4];
#pragma unroll
    for (int ks = 0; ks < 4; ++ks) rfrag[ks] = Fb[((size_t)tr * 4 + ks) * 64 + lane];

    // wave cg's tile sequence: tc = t*8 + cg -> offset tc*256 = t*2048 + cg*256
    const s16x8* base = Fb + (size_t)cg * 256 + lane;

    unsigned ex0[32], ex1[32];
    float rs = 0.f;
    s16x8 cf[4];

#pragma unroll
    for (int t = 0; t < 32; ++t) {
        LOADT5(cf, t)
        COMPT5(cf, t)
    }

    // rowsum: lane's rs covers row l15 over wave cg's 512 cols
    rs += __shfl_xor(rs, 16);
    rs += __shfl_xor(rs, 32);
    if (lane < 16) lsum[lane][cg] = rs;
    __syncthreads();

    // each wave owns output rows {cg*2, cg*2+1}
    const int r0 = cg * 2, r1 = cg * 2 + 1;
    float s0 = 0.f, s1 = 0.f;
#pragma unroll
    for (int w = 0; w < 8; ++w) { s0 += lsum[r0][w]; s1 += lsum[r1][w]; }
    const float rv0 = 1.f / s0;
    const float rv1 = 1.f / s1;

    float* ob0 = out + ((size_t)b * SEQ + tr * 16 + r0) * SEQ;
    float* ob1 = out + ((size_t)b * SEQ + tr * 16 + r1) * SEQ;
    const unsigned wswz = (unsigned)((l15 & 7) << 4);
    const unsigned rswz0 = (unsigned)((r0 & 7) << 4);
    const unsigned rswz1 = (unsigned)((r1 & 7) << 4);

#pragma unroll
    for (int c = 0; c < 4; ++c) {
        if (c > 0) __syncthreads();     // prior chunk's reads done
        // dump 8 tiles (local tile idx = i*8+cg within the chunk)
#pragma unroll
        for (int i = 0; i < 8; ++i) {
            const int t = c * 8 + i;
            const unsigned byte = ((unsigned)(l15 * 2048 + (i * 8 + cg) * 32 + l4 * 8)) ^ wswz;
            *(uint2*)(lsb + byte) = make_uint2(ex0[t], ex1[t]);
        }
        __syncthreads();
        // write 2 full rows, 4x 1KB contiguous NT stores each
#pragma unroll
        for (int it = 0; it < 4; ++it) {
            const unsigned byA = ((unsigned)(r0 * 2048 + it * 512 + lane * 8)) ^ rswz0;
            const uint2 dA = *(const uint2*)(lsb + byA);
            const float2 a01 = __half22float2(*(const __half2*)&dA.x);
            const float2 a23 = __half22float2(*(const __half2*)&dA.y);
            f32x4 pA;
            pA[0] = a01.x * rv0; pA[1] = a01.y * rv0;
            pA[2] = a23.x * rv0; pA[3] = a23.y * rv0;
            __builtin_nontemporal_store(pA, (f32x4*)(ob0 + c * 1024 + it * 256 + lane * 4));

            const unsigned byB = ((unsigned)(r1 * 2048 + it * 512 + lane * 8)) ^ rswz1;
            const uint2 dB = *(const uint2*)(lsb + byB);
            const float2 b01 = __half22float2(*(const __half2*)&dB.x);
            const float2 b23 = __half22float2(*(const __half2*)&dB.y);
            f32x4 pB;
            pB[0] = b01.x * rv1; pB[1] = b01.y * rv1;
            pB[2] = b23.x * rv1; pB[3] = b23.y * rv1;
            __builtin_nontemporal_store(pB, (f32x4*)(ob1 + c * 1024 + it * 256 + lane * 4));
        }
    }
}

extern "C" void kernel_launch(void* const* d_in, const int* in_sizes, int n_in,
                              void* d_out, int out_size, void* d_ws, size_t ws_size,
                              hipStream_t stream)
{
    const float* query = (const float*)d_in[0];
    // d_in[1] = key (unused by the forward)
    const float* Wq    = (const float*)d_in[2];
    const float* bq    = (const float*)d_in[3];
    const float* wt    = (const float*)d_in[4];
    float* out = (float*)d_out;
    s16x8* F  = (s16x8*)d_ws;                               // 4 MiB
    s16x8* WF = (s16x8*)((char*)d_ws + (size_t)4 * 1024 * 1024);  // 256 KiB

    wq_frag_kernel<<<dim3(256), dim3(64), 0, stream>>>(Wq, wt, WF);
    ctx_norm_kernel<<<dim3(ROWS_TOTAL / 64), dim3(512), 0, stream>>>(query, WF, bq, wt, F);
    gram_fused_kernel<<<dim3(BATCH * TPB), dim3(512), 0, stream>>>(F, out);
}

// Round 14
// 117.117 us; speedup vs baseline: 1.0536x; 1.0253x over previous
//
#include <hip/hip_runtime.h>
#include <hip/hip_fp16.h>

// Problem constants
#define BATCH   4
#define SEQ     4096
#define DMODEL  1024
#define HDIM    120
#define ROWS_TOTAL (BATCH * SEQ)       // 16384
#define TPB     256                    // 16-row tiles per batch (SEQ/16)

typedef float f32x4 __attribute__((ext_vector_type(4)));
typedef short s16x8 __attribute__((ext_vector_type(8)));

// F layout (fragment-ordered ctx): s16x8 F[b][tile][ks][lane]
//   = ctx_n[b][tile*16 + (lane&15)][ks*32 + (lane>>4)*8 .. +8]  (bf16)
#define FRAG_PER_B ((size_t)TPB * 4 * 64)

static __device__ __forceinline__ unsigned short f2bf(float f) {
    unsigned u = __float_as_uint(f);
    u += 0x7FFFu + ((u >> 16) & 1u);   // RNE
    return (unsigned short)(u >> 16);
}
static __device__ __forceinline__ s16x8 pack2x4(f32x4 lo, f32x4 hi) {
    s16x8 r;
#pragma unroll
    for (int i = 0; i < 4; ++i) r[i] = (short)f2bf(lo[i]);
#pragma unroll
    for (int i = 0; i < 4; ++i) r[4 + i] = (short)f2bf(hi[i]);
    return r;
}

// ---------------------------------------------------------------------------
// Kernel W (unchanged): Wq -> WF fragment-ordered bf16, wt folded in.
// ---------------------------------------------------------------------------
__global__ __launch_bounds__(64)
void wq_frag_kernel(const float* __restrict__ Wq, const float* __restrict__ wt,
                    s16x8* __restrict__ WF)
{
    const int lane = threadIdx.x;
    const int l15  = lane & 15;
    const int l4   = lane >> 4;
    const int ct   = blockIdx.x >> 5;
    const int ks   = blockIdx.x & 31;
    const int col  = ct * 16 + l15;

    f32x4 lo = (f32x4){0.f,0.f,0.f,0.f}, hi = lo;
    if (col < HDIM) {
        const float w = wt[col];
        const float* src = Wq + (size_t)col * DMODEL + ks * 32 + l4 * 8;
        lo = *(const f32x4*)(src);
        hi = *(const f32x4*)(src + 4);
#pragma unroll
        for (int i = 0; i < 4; ++i) { lo[i] *= w; hi[i] *= w; }
    }
    WF[((size_t)(ct * 32 + ks)) * 64 + lane] = pack2x4(lo, hi);
}

// ---------------------------------------------------------------------------
// Kernel A (unchanged control, == R11): context GEMM + bias + L2-norm -> F.
// ---------------------------------------------------------------------------
__global__ __launch_bounds__(512)
void ctx_norm_kernel(const float* __restrict__ query,
                     const s16x8* __restrict__ WF,
                     const float* __restrict__ bq,
                     const float* __restrict__ wt,
                     s16x8* __restrict__ F)
{
    __shared__ unsigned short lA[2][64 * 40];
    __shared__ float lsq[64][2];
    __shared__ unsigned short lt[64][136];

    const int tid  = threadIdx.x;
    const int lane = tid & 63;
    const int wv   = tid >> 6;
    const int wr   = wv & 3;
    const int wc   = wv >> 2;
    const int l15  = lane & 15;
    const int l4   = lane >> 4;
    const int row0 = blockIdx.x * 64;

    const int arow = tid >> 3, achk = tid & 7;
    const float* aload = query + (size_t)(row0 + arow) * DMODEL + achk * 4;

    f32x4 acc[4];
#pragma unroll
    for (int n = 0; n < 4; ++n) acc[n] = (f32x4){0.f,0.f,0.f,0.f};

    f32x4 pr = *(const f32x4*)(aload);
    {
        const unsigned u0 = (unsigned)f2bf(pr[0]) | ((unsigned)f2bf(pr[1]) << 16);
        const unsigned u1 = (unsigned)f2bf(pr[2]) | ((unsigned)f2bf(pr[3]) << 16);
        *(uint2*)&lA[0][arow * 40 + achk * 4] = make_uint2(u0, u1);
    }

    for (int ks = 0; ks < 32; ++ks) {
        __syncthreads();
        if (ks + 1 < 32) pr = *(const f32x4*)(aload + (ks + 1) * 32);
        const int buf = ks & 1;
        const s16x8 a = *(const s16x8*)&lA[buf][(wr * 16 + l15) * 40 + l4 * 8];
#pragma unroll
        for (int n = 0; n < 4; ++n) {
            const s16x8 bfr = WF[((size_t)((wc * 4 + n) * 32 + ks)) * 64 + lane];
            acc[n] = __builtin_amdgcn_mfma_f32_16x16x32_bf16(a, bfr, acc[n], 0, 0, 0);
        }
        if (ks + 1 < 32) {
            const unsigned u0 = (unsigned)f2bf(pr[0]) | ((unsigned)f2bf(pr[1]) << 16);
            const unsigned u1 = (unsigned)f2bf(pr[2]) | ((unsigned)f2bf(pr[3]) << 16);
            *(uint2*)&lA[buf ^ 1][arow * 40 + achk * 4] = make_uint2(u0, u1);
        }
    }

    float sumsq[4] = {0.f,0.f,0.f,0.f};
#pragma unroll
    for (int n = 0; n < 4; ++n) {
        const int col = wc * 64 + n * 16 + l15;
        const float bqv = (col < HDIM) ? bq[col] * wt[col] : 0.f;
#pragma unroll
        for (int r = 0; r < 4; ++r) {
            const float v = acc[n][r] + bqv;
            acc[n][r] = v;
            sumsq[r] += v * v;
        }
    }
#pragma unroll
    for (int r = 0; r < 4; ++r) {
        float s = sumsq[r];
        s += __shfl_xor(s, 1);
        s += __shfl_xor(s, 2);
        s += __shfl_xor(s, 4);
        s += __shfl_xor(s, 8);
        sumsq[r] = s;
    }
    if (l15 == 0) {
#pragma unroll
        for (int r = 0; r < 4; ++r)
            lsq[wr * 16 + l4 * 4 + r][wc] = sumsq[r];
    }
    __syncthreads();
#pragma unroll
    for (int r = 0; r < 4; ++r) {
        const int lr = wr * 16 + l4 * 4 + r;
        const float s = lsq[lr][0] + lsq[lr][1];
        const float rinv = 1.f / fmaxf(sqrtf(s), 1e-12f);
#pragma unroll
        for (int n = 0; n < 4; ++n)
            lt[lr][wc * 64 + n * 16 + l15] = f2bf(acc[n][r] * rinv);
    }
    __syncthreads();
#pragma unroll
    for (int q = 0; q < 2; ++q) {
        const int idx = wv * 2 + q;
        const int tl  = idx >> 2;
        const int k4  = idx & 3;
        const s16x8 fr = *(const s16x8*)&lt[tl * 16 + l15][k4 * 32 + l4 * 8];
        F[((size_t)(blockIdx.x * 4 + tl) * 4 + k4) * 64 + lane] = fr;
    }
}

// ---------------------------------------------------------------------------
// Kernel B1: rowsum. 512 blocks x 512 thr; block = 32 rows (2 row-tiles) x
// 4096 cols; wave = 512-col strip for BOTH row-tiles (halves L2 reads vs
// 16-row blocks). Zero stores in hot loop, 2-deep register prefetch,
// 2 blocks/CU. Writes rinv[row] = 1/rowsum.
// ---------------------------------------------------------------------------
__global__ __launch_bounds__(512, 4)
void rowsum_kernel(const s16x8* __restrict__ F, float* __restrict__ rinv)
{
    __shared__ float lsum[32][8];

    const int tid  = threadIdx.x;
    const int lane = tid & 63;
    const int cg   = tid >> 6;          // col strip 0..7
    const int l15  = lane & 15;

    const int u    = ((blockIdx.x & 7) << 6) | (blockIdx.x >> 3);  // bijective on 512
    const int b    = u >> 7;
    const int rg   = u & 127;           // 32-row group within batch
    const s16x8* Fb = F + (size_t)b * FRAG_PER_B;

    s16x8 rfA[4], rfB[4];
#pragma unroll
    for (int ks = 0; ks < 4; ++ks) {
        rfA[ks] = Fb[((size_t)(rg * 2) * 4 + ks) * 64 + lane];
        rfB[ks] = Fb[((size_t)(rg * 2 + 1) * 4 + ks) * 64 + lane];
    }

    const s16x8* base = Fb + (size_t)(cg * 32) * 256 + lane;
    float rsA = 0.f, rsB = 0.f;

    s16x8 cf0[4], cf1[4];
    auto loadC = [&](s16x8* cf, int t) {
        const s16x8* p = base + (size_t)t * 256;
#pragma unroll
        for (int ks = 0; ks < 4; ++ks) cf[ks] = p[ks * 64];
    };
    auto accum = [&](const s16x8* cf) {
        f32x4 aA = (f32x4){0.f,0.f,0.f,0.f};
        f32x4 aB = (f32x4){0.f,0.f,0.f,0.f};
#pragma unroll
        for (int ks = 0; ks < 4; ++ks) {
            aA = __builtin_amdgcn_mfma_f32_16x16x32_bf16(cf[ks], rfA[ks], aA, 0, 0, 0);
            aB = __builtin_amdgcn_mfma_f32_16x16x32_bf16(cf[ks], rfB[ks], aB, 0, 0, 0);
        }
#pragma unroll
        for (int j = 0; j < 4; ++j) {
            rsA += __expf(aA[j]);
            rsB += __expf(aB[j]);
        }
    };

    loadC(cf0, 0);
    loadC(cf1, 1);
    for (int t = 0; t < 32; t += 2) {
        accum(cf0);
        if (t + 2 < 32) loadC(cf0, t + 2);
        accum(cf1);
        if (t + 3 < 32) loadC(cf1, t + 3);
    }

    // reduce over l4 groups (rows l15 / 16+l15)
    rsA += __shfl_xor(rsA, 16);
    rsA += __shfl_xor(rsA, 32);
    rsB += __shfl_xor(rsB, 16);
    rsB += __shfl_xor(rsB, 32);
    if (lane < 16) {
        lsum[l15][cg]      = rsA;
        lsum[16 + l15][cg] = rsB;
    }
    __syncthreads();
    if (tid < 32) {
        float s = 0.f;
#pragma unroll
        for (int w = 0; w < 8; ++w) s += lsum[tid][w];
        rinv[(b * 128 + rg) * 32 + tid] = 1.f / s;
    }
}

// ---------------------------------------------------------------------------
// Kernel B2: streaming writer. 512 blocks x 1024 thr; block = 32 rows x 4096
// cols, 4 chunks of 1024 cols. Per chunk: 16 waves compute 8 tiles each
// (exp -> f16 -> LDS, XOR-swizzled), double-buffered 64KB x2; then each wave
// writes 2 FULL ROWS x 1024 floats = 4x 1KB contiguous NT stores. The next
// chunk's F-loads are issued BEFORE this chunk's stores -> stores drain
// under the following MFMA/exp work; writes stream continuously at HBM BW.
// One barrier per chunk. No full-row dependency (rinv precomputed).
// ---------------------------------------------------------------------------
__global__ __launch_bounds__(1024, 4)
void write_stream_kernel(const s16x8* __restrict__ F,
                         const float* __restrict__ rinv,
                         float* __restrict__ out)
{
    __shared__ unsigned short lsb[2][32 * 1024];   // 2 x 64 KB

    const int tid  = threadIdx.x;
    const int lane = tid & 63;
    const int w    = tid >> 6;          // 0..15
    const int rt   = w >> 3;            // row-tile half 0..1
    const int cs   = w & 7;             // col substrip (128 cols)
    const int l15  = lane & 15;
    const int l4   = lane >> 4;

    const int u    = ((blockIdx.x & 7) << 6) | (blockIdx.x >> 3);  // bijective on 512
    const int b    = u >> 7;
    const int rg   = u & 127;
    const s16x8* Fb = F + (size_t)b * FRAG_PER_B;

    s16x8 rfrag[4];
#pragma unroll
    for (int ks = 0; ks < 4; ++ks)
        rfrag[ks] = Fb[((size_t)(rg * 2 + rt) * 4 + ks) * 64 + lane];

    // store rows (local 0..31): wave w owns rows 2w, 2w+1
    const int r0 = 2 * w, r1 = 2 * w + 1;
    const float rv0 = rinv[(b * 128 + rg) * 32 + r0];
    const float rv1 = rinv[(b * 128 + rg) * 32 + r1];
    float* ob0 = out + ((size_t)b * SEQ + rg * 32 + r0) * SEQ;
    float* ob1 = out + ((size_t)b * SEQ + rg * 32 + r1) * SEQ;

    const int  drow  = rt * 16 + l15;                    // dump row 0..31
    const unsigned dswz = (unsigned)((drow & 7) << 4);
    const unsigned sswz0 = (unsigned)((r0 & 7) << 4);
    const unsigned sswz1 = (unsigned)((r1 & 7) << 4);

    auto dump = [&](int c, int buf) {
        char* lb = (char*)&lsb[buf][0];
#pragma unroll
        for (int i = 0; i < 8; ++i) {
            const int tc = c * 64 + cs * 8 + i;
            const s16x8* p = Fb + (size_t)tc * 256 + lane;
            s16x8 cf[4];
#pragma unroll
            for (int ks = 0; ks < 4; ++ks) cf[ks] = p[ks * 64];
            f32x4 a = (f32x4){0.f,0.f,0.f,0.f};
#pragma unroll
            for (int ks = 0; ks < 4; ++ks)
                a = __builtin_amdgcn_mfma_f32_16x16x32_bf16(cf[ks], rfrag[ks], a, 0, 0, 0);
            const __half2 h01 = __floats2half2_rn(__expf(a[0]), __expf(a[1]));
            const __half2 h23 = __floats2half2_rn(__expf(a[2]), __expf(a[3]));
            const unsigned byte = ((unsigned)(drow * 2048 + (cs * 8 + i) * 32 + l4 * 8)) ^ dswz;
            *(uint2*)(lb + byte) = make_uint2(*(const unsigned*)&h01, *(const unsigned*)&h23);
        }
    };
    auto storeph = [&](int c, int buf) {
        const char* lb = (const char*)&lsb[buf][0];
#pragma unroll
        for (int it = 0; it < 4; ++it) {
            const unsigned byA = ((unsigned)(r0 * 2048 + it * 512 + lane * 8)) ^ sswz0;
            const uint2 dA = *(const uint2*)(lb + byA);
            const float2 a01 = __half22float2(*(const __half2*)&dA.x);
            const float2 a23 = __half22float2(*(const __half2*)&dA.y);
            f32x4 pA;
            pA[0] = a01.x * rv0; pA[1] = a01.y * rv0;
            pA[2] = a23.x * rv0; pA[3] = a23.y * rv0;
            __builtin_nontemporal_store(pA, (f32x4*)(ob0 + c * 1024 + it * 256 + lane * 4));

            const unsigned byB = ((unsigned)(r1 * 2048 + it * 512 + lane * 8)) ^ sswz1;
            const uint2 dB = *(const uint2*)(lb + byB);
            const float2 b01 = __half22float2(*(const __half2*)&dB.x);
            const float2 b23 = __half22float2(*(const __half2*)&dB.y);
            f32x4 pB;
            pB[0] = b01.x * rv1; pB[1] = b01.y * rv1;
            pB[2] = b23.x * rv1; pB[3] = b23.y * rv1;
            __builtin_nontemporal_store(pB, (f32x4*)(ob1 + c * 1024 + it * 256 + lane * 4));
        }
    };

    dump(0, 0);
    __syncthreads();
#pragma unroll
    for (int c = 0; c < 4; ++c) {
        if (c < 3) dump(c + 1, (c + 1) & 1);   // issue next chunk's loads first
        storeph(c, c & 1);                      // then stores (drain under next MFMA)
        if (c < 3) __syncthreads();
    }
}

extern "C" void kernel_launch(void* const* d_in, const int* in_sizes, int n_in,
                              void* d_out, int out_size, void* d_ws, size_t ws_size,
                              hipStream_t stream)
{
    const float* query = (const float*)d_in[0];
    // d_in[1] = key (unused by the forward)
    const float* Wq    = (const float*)d_in[2];
    const float* bq    = (const float*)d_in[3];
    const float* wt    = (const float*)d_in[4];
    float* out = (float*)d_out;
    s16x8* F    = (s16x8*)d_ws;                                         // 4 MiB
    s16x8* WF   = (s16x8*)((char*)d_ws + (size_t)4 * 1024 * 1024);      // 256 KiB
    float* rinv = (float*)((char*)d_ws + (size_t)4 * 1024 * 1024 + 256 * 1024);  // 64 KiB

    wq_frag_kernel<<<dim3(256), dim3(64), 0, stream>>>(Wq, wt, WF);
    ctx_norm_kernel<<<dim3(ROWS_TOTAL / 64), dim3(512), 0, stream>>>(query, WF, bq, wt, F);
    rowsum_kernel<<<dim3(512), dim3(512), 0, stream>>>(F, rinv);
    write_stream_kernel<<<dim3(512), dim3(1024), 0, stream>>>(F, rinv, out);
}

// Round 15
// 100.974 us; speedup vs baseline: 1.2220x; 1.1599x over previous
//
#include <hip/hip_runtime.h>
#include <hip/hip_fp16.h>

// Problem constants
#define BATCH   4
#define SEQ     4096
#define DMODEL  1024
#define HDIM    120
#define ROWS_TOTAL (BATCH * SEQ)       // 16384
#define TPB     256                    // 16-row tiles per batch (SEQ/16)

typedef float f32x4 __attribute__((ext_vector_type(4)));
typedef short s16x8 __attribute__((ext_vector_type(8)));

// F layout (fragment-ordered ctx): s16x8 F[global_tile][ks][lane]
//   = ctx_n[tile*16 + (lane&15)][ks*32 + (lane>>4)*8 .. +8]  (bf16)
#define FRAG_PER_B ((size_t)TPB * 4 * 64)
// WF layout (fragment-ordered Wq*wt, bf16): s16x8 WF[(ct*32+ks)*64 + lane]

static __device__ __forceinline__ unsigned short f2bf(float f) {
    unsigned u = __float_as_uint(f);
    u += 0x7FFFu + ((u >> 16) & 1u);   // RNE
    return (unsigned short)(u >> 16);
}
static __device__ __forceinline__ s16x8 pack2x4(f32x4 lo, f32x4 hi) {
    s16x8 r;
#pragma unroll
    for (int i = 0; i < 4; ++i) r[i] = (short)f2bf(lo[i]);
#pragma unroll
    for (int i = 0; i < 4; ++i) r[4 + i] = (short)f2bf(hi[i]);
    return r;
}

// ---------------------------------------------------------------------------
// Kernel W (unchanged): Wq -> WF fragment-ordered bf16, wt folded in.
// ---------------------------------------------------------------------------
__global__ __launch_bounds__(64)
void wq_frag_kernel(const float* __restrict__ Wq, const float* __restrict__ wt,
                    s16x8* __restrict__ WF)
{
    const int lane = threadIdx.x;
    const int l15  = lane & 15;
    const int l4   = lane >> 4;
    const int ct   = blockIdx.x >> 5;
    const int ks   = blockIdx.x & 31;
    const int col  = ct * 16 + l15;

    f32x4 lo = (f32x4){0.f,0.f,0.f,0.f}, hi = lo;
    if (col < HDIM) {
        const float w = wt[col];
        const float* src = Wq + (size_t)col * DMODEL + ks * 32 + l4 * 8;
        lo = *(const f32x4*)(src);
        hi = *(const f32x4*)(src + 4);
#pragma unroll
        for (int i = 0; i < 4; ++i) { lo[i] *= w; hi[i] *= w; }
    }
    WF[((size_t)(ct * 32 + ks)) * 64 + lane] = pack2x4(lo, hi);
}

// ---------------------------------------------------------------------------
// Kernel A v3: context GEMM + bias + L2-norm -> F.
// 512 blocks x 512 thr (2 blocks/CU, 16 waves/CU = 2x R11 occupancy).
// Block = 32 rows; 8 waves = 2 row-groups x 4 col-quarters (32 cols).
// 64-k SLABS: one barrier per 2 K-steps (16 barriers vs R11's 32); each
// thread stages one contiguous f32x4 of query; LDS stride 72 shorts
// (144B, 16B-aligned, 2-way banks = free). WF loads contiguous 1KB.
// ---------------------------------------------------------------------------
__global__ __launch_bounds__(512)
void ctx_norm_kernel(const float* __restrict__ query,
                     const s16x8* __restrict__ WF,
                     const float* __restrict__ bq,
                     const float* __restrict__ wt,
                     s16x8* __restrict__ F)
{
    __shared__ unsigned short lA[2][32 * 72];   // two 64-k slabs
    __shared__ float lsq[32][4];
    __shared__ unsigned short lt[32][136];

    const int tid  = threadIdx.x;
    const int lane = tid & 63;
    const int wv   = tid >> 6;          // 0..7
    const int wr   = wv & 1;            // row-group (16 rows)
    const int wc   = wv >> 1;           // col quarter (32 cols = 2 tiles)
    const int l15  = lane & 15;
    const int l4   = lane >> 4;
    const int row0 = blockIdx.x * 32;

    const int arow = tid >> 4;          // 0..31
    const int achk = tid & 15;          // 16 x f32x4 = 64 k
    const float* aload = query + (size_t)(row0 + arow) * DMODEL + achk * 4;

    f32x4 acc[2];
#pragma unroll
    for (int n = 0; n < 2; ++n) acc[n] = (f32x4){0.f,0.f,0.f,0.f};

    auto stage = [&](int buf, const f32x4& v) {
        const unsigned u0 = (unsigned)f2bf(v[0]) | ((unsigned)f2bf(v[1]) << 16);
        const unsigned u1 = (unsigned)f2bf(v[2]) | ((unsigned)f2bf(v[3]) << 16);
        *(uint2*)&lA[buf][arow * 72 + achk * 4] = make_uint2(u0, u1);
    };

    f32x4 pr = *(const f32x4*)(aload);
    stage(0, pr);

    for (int slab = 0; slab < 16; ++slab) {
        __syncthreads();                      // slab staged; prev slab reads done
        if (slab + 1 < 16) pr = *(const f32x4*)(aload + (slab + 1) * 64);
        const int buf = slab & 1;
#pragma unroll
        for (int ks2 = 0; ks2 < 2; ++ks2) {
            const int ks = slab * 2 + ks2;
            const s16x8 a = *(const s16x8*)&lA[buf][(wr * 16 + l15) * 72 + ks2 * 32 + l4 * 8];
#pragma unroll
            for (int n = 0; n < 2; ++n) {
                const s16x8 bfr = WF[((size_t)((wc * 2 + n) * 32 + ks)) * 64 + lane];
                acc[n] = __builtin_amdgcn_mfma_f32_16x16x32_bf16(a, bfr, acc[n], 0, 0, 0);
            }
        }
        if (slab + 1 < 16) stage(buf ^ 1, pr);
    }

    // epilogue: + bq*wt, row L2-norm (reduce over l15 lanes, then 4 quarters)
    float sumsq[4] = {0.f,0.f,0.f,0.f};
#pragma unroll
    for (int n = 0; n < 2; ++n) {
        const int col = wc * 32 + n * 16 + l15;
        const float bqv = (col < HDIM) ? bq[col] * wt[col] : 0.f;
#pragma unroll
        for (int r = 0; r < 4; ++r) {
            const float v = acc[n][r] + bqv;
            acc[n][r] = v;
            sumsq[r] += v * v;
        }
    }
#pragma unroll
    for (int r = 0; r < 4; ++r) {
        float s = sumsq[r];
        s += __shfl_xor(s, 1);
        s += __shfl_xor(s, 2);
        s += __shfl_xor(s, 4);
        s += __shfl_xor(s, 8);
        sumsq[r] = s;
    }
    if (l15 == 0) {
#pragma unroll
        for (int r = 0; r < 4; ++r)
            lsq[wr * 16 + l4 * 4 + r][wc] = sumsq[r];
    }
    __syncthreads();
#pragma unroll
    for (int r = 0; r < 4; ++r) {
        const int lr = wr * 16 + l4 * 4 + r;
        const float s = lsq[lr][0] + lsq[lr][1] + lsq[lr][2] + lsq[lr][3];
        const float rinv = 1.f / fmaxf(sqrtf(s), 1e-12f);
#pragma unroll
        for (int n = 0; n < 2; ++n)
            lt[lr][wc * 32 + n * 16 + l15] = f2bf(acc[n][r] * rinv);
    }
    __syncthreads();
    // F store: 8 fragments (2 tiles x 4 k-groups), one per wave, 1KB each
    {
        const int tl = wv >> 2;             // 0..1
        const int k4 = wv & 3;              // 0..3
        const s16x8 fr = *(const s16x8*)&lt[tl * 16 + l15][k4 * 32 + l4 * 8];
        F[((size_t)(blockIdx.x * 2 + tl) * 4 + k4) * 64 + lane] = fr;
    }
}

// ---------------------------------------------------------------------------
// Kernel B (EXACT R11 v4, proven 80us): fused single pass, 1024 blocks x
// 1024 thr, block = one 16-row tile x 4096 cols, wave = 256-col strip.
// exp stash -> f16 LDS (XOR-swizzled); write phase: wave w writes output
// row w as 16 x 1KB contiguous NT stores.
// ---------------------------------------------------------------------------
#define LOADT(dst, t) { const s16x8* _p = base + (size_t)(t) * 256;            \
    dst[0] = _p[0]; dst[1] = _p[64]; dst[2] = _p[128]; dst[3] = _p[192]; }

#define COMPT(src, t) { f32x4 _a = (f32x4){0.f, 0.f, 0.f, 0.f};                \
    _a = __builtin_amdgcn_mfma_f32_16x16x32_bf16(src[0], rfrag[0], _a, 0,0,0); \
    _a = __builtin_amdgcn_mfma_f32_16x16x32_bf16(src[1], rfrag[1], _a, 0,0,0); \
    _a = __builtin_amdgcn_mfma_f32_16x16x32_bf16(src[2], rfrag[2], _a, 0,0,0); \
    _a = __builtin_amdgcn_mfma_f32_16x16x32_bf16(src[3], rfrag[3], _a, 0,0,0); \
    const float _e0 = __expf(_a[0]), _e1 = __expf(_a[1]);                      \
    const float _e2 = __expf(_a[2]), _e3 = __expf(_a[3]);                      \
    rs += (_e0 + _e1) + (_e2 + _e3);                                           \
    const __half2 _h01 = __floats2half2_rn(_e0, _e1);                          \
    const __half2 _h23 = __floats2half2_rn(_e2, _e3);                          \
    unsigned _byte = (unsigned)(l15 * 8192 + cg * 512 + (t) * 32 + l4 * 8);    \
    _byte ^= (unsigned)(l15 << 4);                                             \
    *(uint2*)(lsbase + _byte) =                                                \
        make_uint2(*(const unsigned*)&_h01, *(const unsigned*)&_h23); }

__global__ __launch_bounds__(1024)
void gram_fused_kernel(const s16x8* __restrict__ F, float* __restrict__ out)
{
    __shared__ unsigned short lsE[16][4096];    // f16 stash, 128 KB, swizzled
    __shared__ float lsum[16][16];

    const int tid  = threadIdx.x;
    const int lane = tid & 63;
    const int cg   = tid >> 6;          // col strip 0..15 (256 cols)
    const int l15  = lane & 15;
    const int l4   = lane >> 4;
    char* lsbase = (char*)&lsE[0][0];

    // XCD swizzle (bijective on 1024): 128 contiguous row-tiles per XCD
    const int u    = ((blockIdx.x & 7) << 7) | (blockIdx.x >> 3);
    const int b    = u >> 8;
    const int tr   = u & 255;
    const s16x8* Fb = F + (size_t)b * FRAG_PER_B;

    s16x8 rfrag[4];
#pragma unroll
    for (int ks = 0; ks < 4; ++ks) rfrag[ks] = Fb[((size_t)tr * 4 + ks) * 64 + lane];

    const s16x8* base = Fb + (size_t)(cg * 16) * 256 + lane;

    float rs = 0.f;
    s16x8 cA[4], cB[4], cC[4];
    LOADT(cA, 0)
    LOADT(cB, 1)
    LOADT(cC, 2)
#pragma unroll
    for (int i = 0; i < 6; ++i) {
        const int t = i * 3;
        { COMPT(cA, t)           if (t + 3 < 16) LOADT(cA, t + 3) }
        if (t + 1 < 16) { COMPT(cB, t + 1) if (t + 4 < 16) LOADT(cB, t + 4) }
        if (t + 2 < 16) { COMPT(cC, t + 2) if (t + 5 < 16) LOADT(cC, t + 5) }
    }

    // rowsum partials: l4 groups hold partial sums of row l15
    rs += __shfl_xor(rs, 16);
    rs += __shfl_xor(rs, 32);
    if (lane < 16) lsum[lane][cg] = rs;
    __syncthreads();                     // lsE + lsum complete

    // write phase: wave cg owns output row cg of this tile
    float s = 0.f;
#pragma unroll
    for (int w = 0; w < 16; ++w) s += lsum[cg][w];
    const float rv = 1.f / s;

    float* ob = out + ((size_t)b * SEQ + tr * 16 + cg) * SEQ;
    const unsigned swz = (unsigned)(cg << 4);
#pragma unroll
    for (int it = 0; it < 16; ++it) {
        // read addr un-swizzles -> data fetched is LOGICAL col-chunk lane*4
        const unsigned sbyte = (unsigned)(cg * 8192 + it * 512 + lane * 8) ^ swz;
        const uint2 d = *(const uint2*)(lsbase + sbyte);
        const float2 f01 = __half22float2(*(const __half2*)&d.x);
        const float2 f23 = __half22float2(*(const __half2*)&d.y);
        f32x4 pv;
        pv[0] = f01.x * rv;
        pv[1] = f01.y * rv;
        pv[2] = f23.x * rv;
        pv[3] = f23.y * rv;
        __builtin_nontemporal_store(pv, (f32x4*)(ob + it * 256 + lane * 4));
    }
}

extern "C" void kernel_launch(void* const* d_in, const int* in_sizes, int n_in,
                              void* d_out, int out_size, void* d_ws, size_t ws_size,
                              hipStream_t stream)
{
    const float* query = (const float*)d_in[0];
    // d_in[1] = key (unused by the forward)
    const float* Wq    = (const float*)d_in[2];
    const float* bq    = (const float*)d_in[3];
    const float* wt    = (const float*)d_in[4];
    float* out = (float*)d_out;
    s16x8* F  = (s16x8*)d_ws;                               // 4 MiB
    s16x8* WF = (s16x8*)((char*)d_ws + (size_t)4 * 1024 * 1024);  // 256 KiB

    wq_frag_kernel<<<dim3(256), dim3(64), 0, stream>>>(Wq, wt, WF);
    ctx_norm_kernel<<<dim3(ROWS_TOTAL / 32), dim3(512), 0, stream>>>(query, WF, bq, wt, F);
    gram_fused_kernel<<<dim3(BATCH * TPB), dim3(1024), 0, stream>>>(F, out);
}